// Round 11
// baseline (236.328 us; speedup 1.0000x reference)
//
#include <hip/hip_runtime.h>

#define N_NODES 50000
#define N_EDGES 800000
#define NG      128
#define FIN     64
#define HD      108
#define SCAN_B  49          // ceil(50000/1024)
#define CNT_B   782         // count blocks in mix_k (ceil(800000/1024), 4 edges/thread)
#define DEGP    16          // deg counter stride in ints (64 B -> 1 counter/line)

typedef __attribute__((ext_vector_type(8))) short s16x8;   // 8 bf16 = 4 VGPRs
typedef __attribute__((ext_vector_type(4))) float f32x4;

__device__ __forceinline__ unsigned short bf16_rne(float x) {
    unsigned u = __float_as_uint(x);
    u += 0x7FFFu + ((u >> 16) & 1u);
    return (unsigned short)(u >> 16);
}
__device__ __forceinline__ float bf16_to_f(unsigned u16) {
    return __uint_as_float(u16 << 16);
}

// ---------------------------------------------------------------------------
// Fused prep. block ranges:
// [0,1563) fconv | [1563,1759) hc pad zero | [1759,1801) wprep |
// [1801,2583) deg_p zero | [2583,2597) gsum zero (+done) | [2597] gcnt
// Weight tiles (24 kst x 7 nt): emb 0..1 | p1 2..5 | n1 6..12 | p2 13..16 | n2 17..23
// ---------------------------------------------------------------------------
__global__ void prep_k(const float* __restrict__ feat, unsigned short* __restrict__ fbf,
                       unsigned short* __restrict__ hc,
                       const float* __restrict__ W0, const float* __restrict__ W1,
                       const float* __restrict__ W2, const float* __restrict__ W3,
                       const float* __restrict__ W4, unsigned short* __restrict__ Wf,
                       int* __restrict__ deg_p, float* __restrict__ gsum,
                       const int* __restrict__ gids, int* __restrict__ gcnt,
                       int* __restrict__ done) {
    int b = blockIdx.x, t = threadIdx.x;
    if (b < 1563) {                                   // feat f32 -> bf16, 8/thread
        int i = b * 256 + t;
        if (i < N_NODES * FIN / 8) {
            const float4* p = (const float4*)(feat + (size_t)i * 8);
            float4 a = p[0], c = p[1];
            s16x8 o;
            o[0] = (short)bf16_rne(a.x); o[1] = (short)bf16_rne(a.y);
            o[2] = (short)bf16_rne(a.z); o[3] = (short)bf16_rne(a.w);
            o[4] = (short)bf16_rne(c.x); o[5] = (short)bf16_rne(c.y);
            o[6] = (short)bf16_rne(c.z); o[7] = (short)bf16_rne(c.w);
            *(s16x8*)(fbf + (size_t)i * 8) = o;
        }
    } else if (b < 1759) {                            // hc cols 216..223 = 0
        int i = (b - 1563) * 256 + t;
        if (i < N_NODES) {
            s16x8 z = {0, 0, 0, 0, 0, 0, 0, 0};
            *(s16x8*)(hc + (size_t)i * 224 + 216) = z;
        }
    } else if (b < 1801) {                            // weight repack, 1 tile/wave
        int tile = (b - 1759) * 4 + (t >> 6), lane = t & 63;
        if (tile < 168) {
            int kst = tile / 7, nt = tile % 7;
            const float* W; int Kr, ks;
            if (kst < 2)       { W = W0; Kr = 64;  ks = kst;      }
            else if (kst < 6)  { W = W1; Kr = 108; ks = kst - 2;  }
            else if (kst < 13) { W = W2; Kr = 216; ks = kst - 6;  }
            else if (kst < 17) { W = W3; Kr = 108; ks = kst - 13; }
            else               { W = W4; Kr = 216; ks = kst - 17; }
            int n = nt * 16 + (lane & 15);
            s16x8 o;
            #pragma unroll
            for (int j = 0; j < 8; ++j) {
                int k = ks * 32 + (lane >> 4) * 8 + j;
                float v = (k < Kr && n < HD) ? W[k * HD + n] : 0.0f;
                o[j] = (short)bf16_rne(v);
            }
            *(s16x8*)(Wf + (size_t)tile * 512 + lane * 8) = o;
        }
    } else if (b < 2583) {                            // deg_p = 0 (3.2 MB, int4)
        int i = (b - 1801) * 256 + t;
        if (i < N_NODES * DEGP / 4) ((int4*)deg_p)[i] = (int4){0, 0, 0, 0};
    } else if (b < 2597) {                            // gsum = 0 (+done)
        int i = (b - 2583) * 256 + t;
        if (i < NG * HD / 4) ((int4*)gsum)[i] = (int4){0, 0, 0, 0};
        if (b == 2583 && t == 0) *done = 0;
    } else {                                          // per-graph counts (sorted)
        int g = t;
        if (g < NG) {
            int lo = 0, hi = N_NODES;
            while (lo < hi) { int mid = (lo + hi) >> 1; if (gids[mid] < g) lo = mid + 1; else hi = mid; }
            int s = lo;
            lo = s; hi = N_NODES;
            while (lo < hi) { int mid = (lo + hi) >> 1; if (gids[mid] < g + 1) lo = mid + 1; else hi = mid; }
            gcnt[g] = lo - s;
        }
    }
}

// ---------------------------------------------------------------------------
// scan1 + fused scan2 tail (last-block-done). rowp[i] stays CHUNK-LOCAL
// exclusive; boff[chunk] is added inline by consumers. Also emits cursor[] =
// same chunk-local starts, used by fill_k's fetch-add slot allocation.
// ---------------------------------------------------------------------------
__global__ void scan1_k(const int* __restrict__ deg_p, int* __restrict__ rowp,
                        int* __restrict__ cursor,
                        int* __restrict__ bsum, int* __restrict__ boff,
                        int* __restrict__ done) {
    __shared__ int s_w[16];
    __shared__ int s_last;
    int t = threadIdx.x, lane = t & 63, wid = t >> 6;
    int i = blockIdx.x * 1024 + t;
    int v = (i < N_NODES) ? deg_p[(size_t)i * DEGP] : 0;
    int x = v;
    #pragma unroll
    for (int off = 1; off < 64; off <<= 1) {
        int y = __shfl_up(x, off);
        if (lane >= off) x += y;
    }
    if (lane == 63) s_w[wid] = x;
    __syncthreads();
    if (t < 16) {
        int y = s_w[t];
        #pragma unroll
        for (int off = 1; off < 16; off <<= 1) {
            int z = __shfl_up(y, off);
            if (t >= off) y += z;
        }
        s_w[t] = y;
    }
    __syncthreads();
    int woff = wid ? s_w[wid - 1] : 0;
    if (i < N_NODES) {
        int ex = woff + x - v;                        // chunk-local exclusive
        rowp[i]   = ex;
        cursor[i] = ex;
    }
    if (t == 1023) {
        bsum[blockIdx.x] = s_w[15];
        __threadfence();                              // release bsum
        s_last = (atomicAdd(done, 1) == SCAN_B - 1);
    }
    __syncthreads();
    if (s_last) {
        __threadfence();                              // acquire all bsum
        if (t < 64) {
            int v2 = (t < SCAN_B) ? bsum[t] : 0;
            int x2 = v2;
            #pragma unroll
            for (int off = 1; off < 64; off <<= 1) {
                int y2 = __shfl_up(x2, off);
                if (t >= off) x2 += y2;
            }
            if (t < SCAN_B) boff[t] = x2 - v2;        // exclusive chunk offsets
            if (t == SCAN_B - 1) rowp[N_NODES] = x2;  // total = E
        }
    }
}

// fill via per-node cursor fetch-add; 4 edges/thread so the 4 atomic
// round-trips overlap (MLP). Intra-bucket order = arrival order.
__global__ void fill_k(const int* __restrict__ src, const int* __restrict__ dst,
                       int* __restrict__ cursor, const int* __restrict__ boff,
                       int* __restrict__ csr) {
    int e0 = blockIdx.x * 1024 + threadIdx.x;
    #pragma unroll
    for (int k = 0; k < 4; ++k) {
        int e = e0 + k * 256;
        if (e < N_EDGES) {
            int d = dst[e];
            int idx = atomicAdd(&cursor[d], 1) + boff[d >> 10];
            csr[idx] = src[e];
        }
    }
}

// ---------------------------------------------------------------------------
// Shared GEMM body. One wave = 16 nodes x 112 cols.
// EPI: 0=embed+pool, 2=apply+pool, 3=apply-final(graph-sum atomics).
// m layout: CHUNKED m[ch][node][32] bf16, ch = col/32 (chunk 3: cols 96..111
// in shorts 0..15, shorts 16..31 unused). Chunk = 3.2 MB -> one XCD's L2.
// ---------------------------------------------------------------------------
template <int KSTEPS, int EPI>
__device__ __forceinline__ void gemm_body(
    int blk,
    const unsigned short* __restrict__ A, int strideA,
    const unsigned short* __restrict__ Wf, const float* __restrict__ bias,
    const unsigned short* __restrict__ Wfp, const float* __restrict__ biasp,
    unsigned short* __restrict__ hc, unsigned short* __restrict__ m_out,
    const int* __restrict__ gids, float* __restrict__ gsum) {
    __shared__ unsigned short s_t[4][16][136];
    int t = threadIdx.x, lane = t & 63, wave = t >> 6;
    int wrow = (blk * 4 + wave) * 16;
    if (wrow >= N_NODES) return;
    int l15 = lane & 15, lg = lane >> 4;

    f32x4 acc[7];
    #pragma unroll
    for (int nt = 0; nt < 7; ++nt) acc[nt] = (f32x4){0.f, 0.f, 0.f, 0.f};

    const unsigned short* arow = A + (size_t)(wrow + l15) * strideA + lg * 8;
    #pragma unroll
    for (int ks = 0; ks < KSTEPS; ++ks) {
        s16x8 a = *(const s16x8*)(arow + ks * 32);
        const unsigned short* wp = Wf + ((size_t)(ks * 7) * 64 + lane) * 8;
        #pragma unroll
        for (int nt = 0; nt < 7; ++nt) {
            s16x8 bfr = *(const s16x8*)(wp + (size_t)nt * 512);
            acc[nt] = __builtin_amdgcn_mfma_f32_16x16x32_bf16(a, bfr, acc[nt], 0, 0, 0);
        }
    }

    // D layout: col = nt*16 + l15, row(local) = lg*4 + r
    float vals[7][4];
    if (EPI == 0) {                                   // embed: + bias
        #pragma unroll
        for (int nt = 0; nt < 7; ++nt) {
            int col = nt * 16 + l15;
            float bv = (col < HD) ? bias[col] : 0.0f;
            #pragma unroll
            for (int r = 0; r < 4; ++r) vals[nt][r] = acc[nt][r] + bv;
        }
    } else {                                          // apply: norm + residual
        float ss[4] = {0.f, 0.f, 0.f, 0.f};
        #pragma unroll
        for (int nt = 0; nt < 7; ++nt) {
            int col = nt * 16 + l15;
            bool valid = (col < HD);
            float bv = valid ? bias[col] : 0.0f;
            #pragma unroll
            for (int r = 0; r < 4; ++r) {
                float v = valid ? (acc[nt][r] + bv) : 0.0f;
                vals[nt][r] = v;
                ss[r] += v * v;
            }
        }
        #pragma unroll
        for (int r = 0; r < 4; ++r) {
            ss[r] += __shfl_xor(ss[r], 1);
            ss[r] += __shfl_xor(ss[r], 2);
            ss[r] += __shfl_xor(ss[r], 4);
            ss[r] += __shfl_xor(ss[r], 8);
        }
        float rn[4];
        #pragma unroll
        for (int r = 0; r < 4; ++r) rn[r] = 1.0f / fmaxf(sqrtf(ss[r]), 1e-12f);
        #pragma unroll
        for (int nt = 0; nt < 7; ++nt) {
            int col = nt * 16 + l15;
            bool valid = (col < HD);
            #pragma unroll
            for (int r = 0; r < 4; ++r) {
                int row = wrow + lg * 4 + r;
                float hv = valid ? bf16_to_f(hc[(size_t)row * 224 + col]) : 0.0f;
                vals[nt][r] = hv + fmaxf(vals[nt][r] * rn[r], 0.0f);
            }
        }
    }

    if (EPI == 3) {                                   // graph-mean accumulation
        int g0 = gids[wrow], g15 = gids[wrow + 15];
        if (g0 == g15) {
            #pragma unroll
            for (int nt = 0; nt < 7; ++nt) {
                int col = nt * 16 + l15;
                float cs = vals[nt][0] + vals[nt][1] + vals[nt][2] + vals[nt][3];
                cs += __shfl_xor(cs, 16);
                cs += __shfl_xor(cs, 32);
                if (lane < 16 && col < HD) atomicAdd(&gsum[g0 * HD + col], cs);
            }
        } else {
            int gr[4];
            #pragma unroll
            for (int r = 0; r < 4; ++r) gr[r] = gids[wrow + lg * 4 + r];
            #pragma unroll
            for (int nt = 0; nt < 7; ++nt) {
                int col = nt * 16 + l15;
                if (col >= HD) continue;
                #pragma unroll
                for (int r = 0; r < 4; ++r)
                    atomicAdd(&gsum[gr[r] * HD + col], vals[nt][r]);
            }
        }
        return;
    }

    // transpose h into LDS (cols >=108 forced 0), zero pad cols 112..127
    #pragma unroll
    for (int nt = 0; nt < 7; ++nt) {
        int col = nt * 16 + l15;
        #pragma unroll
        for (int r = 0; r < 4; ++r) {
            unsigned short hb = (col < HD) ? bf16_rne(vals[nt][r]) : 0;
            s_t[wave][lg * 4 + r][col] = hb;
        }
    }
    #pragma unroll
    for (int p = 0; p < 2; ++p) {                     // 16 rows x 8 uints (cols 112..127)
        int idx = p * 64 + lane;
        int row = idx >> 3, q = idx & 7;
        *(unsigned*)&s_t[wave][row][112 + q * 2] = 0u;
    }

    // h store: 14 segs x 16B per row
    #pragma unroll
    for (int p = 0; p < 4; ++p) {
        int seg = p * 4 + lg;
        if (seg < 14)
            *(s16x8*)(hc + (size_t)(wrow + l15) * 224 + seg * 8) =
                *(const s16x8*)&s_t[wave][l15][seg * 8];
    }

    // pool: m = relu(h @ Wp + bp), A-fragments from LDS transpose
    f32x4 accp[7];
    #pragma unroll
    for (int nt = 0; nt < 7; ++nt) accp[nt] = (f32x4){0.f, 0.f, 0.f, 0.f};
    #pragma unroll
    for (int ks = 0; ks < 4; ++ks) {
        s16x8 a = *(const s16x8*)&s_t[wave][l15][ks * 32 + lg * 8];
        const unsigned short* wp = Wfp + ((size_t)(ks * 7) * 64 + lane) * 8;
        #pragma unroll
        for (int nt = 0; nt < 7; ++nt) {
            s16x8 bfr = *(const s16x8*)(wp + (size_t)nt * 512);
            accp[nt] = __builtin_amdgcn_mfma_f32_16x16x32_bf16(a, bfr, accp[nt], 0, 0, 0);
        }
    }
    // transpose m into LDS, then chunked aligned 16B stores
    #pragma unroll
    for (int nt = 0; nt < 7; ++nt) {
        int col = nt * 16 + l15;
        float bv = (col < HD) ? biasp[col] : 0.0f;
        #pragma unroll
        for (int r = 0; r < 4; ++r)
            s_t[wave][lg * 4 + r][col] = bf16_rne(fmaxf(accp[nt][r] + bv, 0.0f));
    }
    #pragma unroll
    for (int p = 0; p < 4; ++p) {
        int seg = p * 4 + lg;
        if (seg < 14) {
            int ch = seg >> 2, sub = seg & 3;
            *(s16x8*)(m_out + ((size_t)ch * N_NODES + (wrow + l15)) * 32 + sub * 8) =
                *(const s16x8*)&s_t[wave][l15][seg * 8];
        }
    }
}

template <int KSTEPS, int EPI>
__global__ __launch_bounds__(256) void gemm_k(
    const unsigned short* __restrict__ A, int strideA,
    const unsigned short* __restrict__ Wf, const float* __restrict__ bias,
    const unsigned short* __restrict__ Wfp, const float* __restrict__ biasp,
    unsigned short* __restrict__ hc, unsigned short* __restrict__ m_out,
    const int* __restrict__ gids, float* __restrict__ gsum) {
    gemm_body<KSTEPS, EPI>(blockIdx.x, A, strideA, Wf, bias, Wfp, biasp,
                           hc, m_out, gids, gsum);
}

// ---------------------------------------------------------------------------
// mix: fire-and-forget edge counting (no return -> no waitcnt; 4 edges/thread)
//      || embed+pool1 (MFMA) — independent work in one dispatch
// ---------------------------------------------------------------------------
__global__ __launch_bounds__(256) void mix_k(
    const int* __restrict__ dst, int* __restrict__ deg_p,
    const unsigned short* __restrict__ fbf,
    const unsigned short* __restrict__ Wf_emb, const float* __restrict__ bemb,
    const unsigned short* __restrict__ Wf_p1, const float* __restrict__ bp1,
    unsigned short* __restrict__ hc, unsigned short* __restrict__ m_out) {
    if (blockIdx.x < CNT_B) {
        int e0 = blockIdx.x * 1024 + threadIdx.x;
        #pragma unroll
        for (int k = 0; k < 4; ++k) {
            int e = e0 + k * 256;
            if (e < N_EDGES) atomicAdd(&deg_p[(size_t)dst[e] * DEGP], 1);
        }
    } else {
        gemm_body<2, 0>(blockIdx.x - CNT_B, fbf, FIN, Wf_emb, bemb, Wf_p1, bp1,
                        hc, m_out, nullptr, nullptr);
    }
}

// ---------------------------------------------------------------------------
// Chunked, software-pipelined aggregation (round-9 structure), boff inline.
// ---------------------------------------------------------------------------
__global__ __launch_bounds__(256) void aggregate_k(
    const unsigned short* __restrict__ m,
    const int* __restrict__ rowp, const int* __restrict__ boff,
    const int* __restrict__ csr, unsigned short* __restrict__ hc) {
    int chunk = blockIdx.x & 3;
    int nblk  = blockIdx.x >> 2;
    int t = threadIdx.x, lane = t & 63, wave = t >> 6;
    int v = nblk * 64 + wave * 16 + (lane >> 2);
    if (v >= N_NODES) return;
    int sub = lane & 3;
    int co = sub * 8;                                 // within-chunk col offset
    int gcol = chunk * 32 + co;                       // global m/c column
    bool active = (gcol < 112);                       // chunk-3 upper half: mask only
    int grp = lane & ~3;
    const unsigned short* mc = m + (size_t)chunk * N_NODES * 32 + co;
    int beg = rowp[v] + boff[v >> 10];
    int end = (v + 1 < N_NODES) ? rowp[v + 1] + boff[(v + 1) >> 10] : rowp[N_NODES];
    float s[8] = {0.f, 0.f, 0.f, 0.f, 0.f, 0.f, 0.f, 0.f};

    int i = beg;
    int p0 = i + sub, p1 = i + 4 + sub;
    int c0 = (p0 < end) ? csr[p0] : -1;
    int c1 = (p1 < end) ? csr[p1] : -1;
    while (i < end) {
        int ni = i + 8;
        int n0 = -1, n1 = -1;
        if (ni < end) {                               // prefetch next batch early
            int q0 = ni + sub, q1 = ni + 4 + sub;
            n0 = (q0 < end) ? csr[q0] : -1;
            n1 = (q1 < end) ? csr[q1] : -1;
        }
        #pragma unroll
        for (int j = 0; j < 4; ++j) {
            int sv = __shfl(c0, grp + j);
            if (sv >= 0 && active) {
                s16x8 a = *(const s16x8*)(mc + (size_t)sv * 32);
                #pragma unroll
                for (int q = 0; q < 8; ++q) s[q] += bf16_to_f((unsigned short)a[q]);
            }
        }
        #pragma unroll
        for (int j = 0; j < 4; ++j) {
            int sv = __shfl(c1, grp + j);
            if (sv >= 0 && active) {
                s16x8 a = *(const s16x8*)(mc + (size_t)sv * 32);
                #pragma unroll
                for (int q = 0; q < 8; ++q) s[q] += bf16_to_f((unsigned short)a[q]);
            }
        }
        c0 = n0; c1 = n1; i = ni;
    }

    if (active) {
        int degv = end - beg;
        float inv = (degv > 0) ? 1.0f / (float)degv : 0.0f;
        unsigned short* dstp = hc + (size_t)v * 224 + HD + gcol;
        #pragma unroll
        for (int j2 = 0; j2 < 4; ++j2) {
            unsigned pk = (unsigned)bf16_rne(s[2 * j2] * inv) |
                          ((unsigned)bf16_rne(s[2 * j2 + 1] * inv) << 16);
            *(unsigned*)(dstp + 2 * j2) = pk;
        }
    }
}

__global__ void finalize_k(const float* __restrict__ gsum, const int* __restrict__ gcnt,
                           float* __restrict__ out) {
    int i = blockIdx.x * 256 + threadIdx.x;
    if (i < NG * HD) {
        int g = i / HD;
        int cnt = gcnt[g];
        float inv = (cnt > 0) ? 1.0f / (float)cnt : 0.0f;
        out[i] = gsum[i] * inv;
    }
}

// ---------------------------------------------------------------------------
extern "C" void kernel_launch(void* const* d_in, const int* in_sizes, int n_in,
                              void* d_out, int out_size, void* d_ws, size_t ws_size,
                              hipStream_t stream) {
    const float* feat = (const float*)d_in[0];
    const int* src  = (const int*)d_in[4];
    const int* dst  = (const int*)d_in[5];
    const int* gids = (const int*)d_in[6];
    const float* Wemb = (const float*)d_in[7];
    const float* bemb = (const float*)d_in[8];
    const float* Wp1  = (const float*)d_in[9];
    const float* bp1  = (const float*)d_in[10];
    const float* Wn1  = (const float*)d_in[11];
    const float* bn1  = (const float*)d_in[12];
    const float* Wp2  = (const float*)d_in[13];
    const float* bp2  = (const float*)d_in[14];
    const float* Wn2  = (const float*)d_in[15];
    const float* bn2  = (const float*)d_in[16];
    float* out = (float*)d_out;
    (void)in_sizes; (void)n_in; (void)out_size; (void)ws_size;

    char* ws = (char*)d_ws;
    size_t off = 0;
    auto carve = [&](size_t bytes) -> char* {
        char* p = ws + off;
        off = (off + bytes + 255) & ~(size_t)255;
        return p;
    };
    unsigned short* hc    = (unsigned short*)carve((size_t)N_NODES * 224 * 2);
    unsigned short* m_bf  = (unsigned short*)carve((size_t)4 * N_NODES * 32 * 2);
    unsigned short* fbf   = (unsigned short*)carve((size_t)N_NODES * FIN * 2);
    unsigned short* Wf    = (unsigned short*)carve((size_t)24 * 7 * 512 * 2);
    int* deg_p  = (int*)carve((size_t)N_NODES * DEGP * 4);
    int* rowp   = (int*)carve((size_t)(N_NODES + 1) * 4);
    int* cursor = (int*)carve((size_t)N_NODES * 4);
    int* csr    = (int*)carve((size_t)N_EDGES * 4);
    int* bsum   = (int*)carve((size_t)SCAN_B * 4);
    int* boff   = (int*)carve((size_t)SCAN_B * 4);
    float* gsum = (float*)carve((size_t)NG * HD * 4);
    int*   gcnt = (int*)carve((size_t)NG * 4);
    int*   done = (int*)carve(4);

    // fused prep: fconv + hc-pad + repack + deg_p/gsum/done zero + gcnt
    prep_k<<<2598, 256, 0, stream>>>(feat, fbf, hc, Wemb, Wp1, Wn1, Wp2, Wn2, Wf,
                                     deg_p, gsum, gids, gcnt, done);

    const int GB = (N_NODES / 16 + 3) / 4;           // 782 blocks x 4 waves
    const int AB = 4 * ((N_NODES + 63) / 64);        // 4 chunks x 782 node-blocks
    unsigned short* Wf_emb = Wf + (size_t)0  * 7 * 512;
    unsigned short* Wf_p1  = Wf + (size_t)2  * 7 * 512;
    unsigned short* Wf_n1  = Wf + (size_t)6  * 7 * 512;
    unsigned short* Wf_p2  = Wf + (size_t)13 * 7 * 512;
    unsigned short* Wf_n2  = Wf + (size_t)17 * 7 * 512;

    // count (fire-and-forget atomics) || embed+pool1 in one dispatch
    mix_k<<<CNT_B + GB, 256, 0, stream>>>(dst, deg_p, fbf, Wf_emb, bemb,
                                          Wf_p1, bp1, hc, m_bf);

    scan1_k<<<SCAN_B, 1024, 0, stream>>>(deg_p, rowp, cursor, bsum, boff, done);
    fill_k<<<CNT_B, 256, 0, stream>>>(src, dst, cursor, boff, csr);

    // layer 1
    aggregate_k<<<AB, 256, 0, stream>>>(m_bf, rowp, boff, csr, hc);
    gemm_k<7, 2><<<GB, 256, 0, stream>>>(hc, 224, Wf_n1, bn1, Wf_p2, bp2,
                                         hc, m_bf, nullptr, nullptr);
    // layer 2
    aggregate_k<<<AB, 256, 0, stream>>>(m_bf, rowp, boff, csr, hc);
    gemm_k<7, 3><<<GB, 256, 0, stream>>>(hc, 224, Wf_n2, bn2, nullptr, nullptr,
                                         hc, nullptr, gids, gsum);

    finalize_k<<<(NG * HD + 255) / 256, 256, 0, stream>>>(gsum, gcnt, out);
}

// Round 12
// 185.955 us; speedup vs baseline: 1.2709x; 1.2709x over previous
//
#include <hip/hip_runtime.h>

#define N_NODES 50000
#define N_EDGES 800000
#define NG      128
#define FIN     64
#define HD      108
#define SCAN_B  49          // ceil(50000/1024)
#define CNT_B   3125        // count blocks inside mix_k (800000/256)
#define DEGP    4           // deg counter stride in ints (16 B)

typedef __attribute__((ext_vector_type(8))) short s16x8;   // 8 bf16 = 4 VGPRs
typedef __attribute__((ext_vector_type(4))) float f32x4;

__device__ __forceinline__ unsigned short bf16_rne(float x) {
    unsigned u = __float_as_uint(x);
    u += 0x7FFFu + ((u >> 16) & 1u);
    return (unsigned short)(u >> 16);
}
__device__ __forceinline__ float bf16_to_f(unsigned u16) {
    return __uint_as_float(u16 << 16);
}

// ---------------------------------------------------------------------------
// Fused prep. block ranges:
// [0,196) hc pad zero | [196,238) wprep | [238,434) deg_p zero |
// [434,448) gsum zero (+done) | [448] gcnt
// Weight tiles (24 kst x 7 nt): emb 0..1 | p1 2..5 | n1 6..12 | p2 13..16 | n2 17..23
// ---------------------------------------------------------------------------
__global__ void prep_k(unsigned short* __restrict__ hc,
                       const float* __restrict__ W0, const float* __restrict__ W1,
                       const float* __restrict__ W2, const float* __restrict__ W3,
                       const float* __restrict__ W4, unsigned short* __restrict__ Wf,
                       int* __restrict__ deg_p, float* __restrict__ gsum,
                       const int* __restrict__ gids, int* __restrict__ gcnt,
                       int* __restrict__ done) {
    int b = blockIdx.x, t = threadIdx.x;
    if (b < 196) {                                    // hc cols 216..223 = 0
        int i = b * 256 + t;
        if (i < N_NODES) {
            s16x8 z = {0, 0, 0, 0, 0, 0, 0, 0};
            *(s16x8*)(hc + (size_t)i * 224 + 216) = z;
        }
    } else if (b < 238) {                             // weight repack, 1 tile/wave
        int tile = (b - 196) * 4 + (t >> 6), lane = t & 63;
        if (tile < 168) {
            int kst = tile / 7, nt = tile % 7;
            const float* W; int Kr, ks;
            if (kst < 2)       { W = W0; Kr = 64;  ks = kst;      }
            else if (kst < 6)  { W = W1; Kr = 108; ks = kst - 2;  }
            else if (kst < 13) { W = W2; Kr = 216; ks = kst - 6;  }
            else if (kst < 17) { W = W3; Kr = 108; ks = kst - 13; }
            else               { W = W4; Kr = 216; ks = kst - 17; }
            int n = nt * 16 + (lane & 15);
            s16x8 o;
            #pragma unroll
            for (int j = 0; j < 8; ++j) {
                int k = ks * 32 + (lane >> 4) * 8 + j;
                float v = (k < Kr && n < HD) ? W[k * HD + n] : 0.0f;
                o[j] = (short)bf16_rne(v);
            }
            *(s16x8*)(Wf + (size_t)tile * 512 + lane * 8) = o;
        }
    } else if (b < 434) {                             // deg_p = 0 (800 KB, int4)
        int i = (b - 238) * 256 + t;
        if (i < N_NODES * DEGP / 4) ((int4*)deg_p)[i] = (int4){0, 0, 0, 0};
    } else if (b < 448) {                             // gsum = 0 (+done)
        int i = (b - 434) * 256 + t;
        if (i < NG * HD / 4) ((int4*)gsum)[i] = (int4){0, 0, 0, 0};
        if (b == 434 && t == 0) *done = 0;
    } else {                                          // per-graph counts (sorted)
        int g = t;
        if (g < NG) {
            int lo = 0, hi = N_NODES;
            while (lo < hi) { int mid = (lo + hi) >> 1; if (gids[mid] < g) lo = mid + 1; else hi = mid; }
            int s = lo;
            lo = s; hi = N_NODES;
            while (lo < hi) { int mid = (lo + hi) >> 1; if (gids[mid] < g + 1) lo = mid + 1; else hi = mid; }
            gcnt[g] = lo - s;
        }
    }
}

// ---------------------------------------------------------------------------
// scan1 + fused scan2 tail (last-block-done). rowp[i] stays CHUNK-LOCAL
// exclusive; boff[chunk] is added inline by consumers.
// ---------------------------------------------------------------------------
__global__ void scan1_k(const int* __restrict__ deg_p, int* __restrict__ rowp,
                        int* __restrict__ bsum, int* __restrict__ boff,
                        int* __restrict__ done) {
    __shared__ int s_w[16];
    __shared__ int s_last;
    int t = threadIdx.x, lane = t & 63, wid = t >> 6;
    int i = blockIdx.x * 1024 + t;
    int v = (i < N_NODES) ? deg_p[(size_t)i * DEGP] : 0;
    int x = v;
    #pragma unroll
    for (int off = 1; off < 64; off <<= 1) {
        int y = __shfl_up(x, off);
        if (lane >= off) x += y;
    }
    if (lane == 63) s_w[wid] = x;
    __syncthreads();
    if (t < 16) {
        int y = s_w[t];
        #pragma unroll
        for (int off = 1; off < 16; off <<= 1) {
            int z = __shfl_up(y, off);
            if (t >= off) y += z;
        }
        s_w[t] = y;
    }
    __syncthreads();
    int woff = wid ? s_w[wid - 1] : 0;
    if (i < N_NODES) rowp[i] = woff + x - v;          // chunk-local exclusive
    if (t == 1023) {
        bsum[blockIdx.x] = s_w[15];
        __threadfence();                              // release bsum
        s_last = (atomicAdd(done, 1) == SCAN_B - 1);
    }
    __syncthreads();
    if (s_last) {
        __threadfence();                              // acquire all bsum
        if (t < 64) {
            int v2 = (t < SCAN_B) ? bsum[t] : 0;
            int x2 = v2;
            #pragma unroll
            for (int off = 1; off < 64; off <<= 1) {
                int y2 = __shfl_up(x2, off);
                if (t >= off) x2 += y2;
            }
            if (t < SCAN_B) boff[t] = x2 - v2;        // exclusive chunk offsets
            if (t == SCAN_B - 1) rowp[N_NODES] = x2;  // total = E
        }
    }
}

__global__ void fill_k(const int* __restrict__ src, const int* __restrict__ dst,
                       const int* __restrict__ rowp, const int* __restrict__ boff,
                       const int* __restrict__ pos, int* __restrict__ csr) {
    int e = blockIdx.x * 256 + threadIdx.x;
    if (e < N_EDGES) {
        int d = dst[e];
        csr[rowp[d] + boff[d >> 10] + pos[e]] = src[e];
    }
}

// ---------------------------------------------------------------------------
// Shared GEMM body. One wave = 16 nodes x 112 cols.
// EPI: 0=embed+pool, 2=apply+pool, 3=apply-final(graph-sum atomics).
// AF32: A operand is f32 (feat) -> convert to bf16 in-register (kills fconv).
// m layout: CHUNKED m[ch][node][32] bf16, ch = col/32 (chunk 3: cols 96..111
// in shorts 0..15, shorts 16..31 unused). Chunk = 3.2 MB -> one XCD's L2.
// ---------------------------------------------------------------------------
template <int KSTEPS, int EPI, bool AF32>
__device__ __forceinline__ void gemm_body(
    int blk,
    const void* __restrict__ Aptr, int strideA,
    const unsigned short* __restrict__ Wf, const float* __restrict__ bias,
    const unsigned short* __restrict__ Wfp, const float* __restrict__ biasp,
    unsigned short* __restrict__ hc, unsigned short* __restrict__ m_out,
    const int* __restrict__ gids, float* __restrict__ gsum) {
    __shared__ unsigned short s_t[4][16][136];
    int t = threadIdx.x, lane = t & 63, wave = t >> 6;
    int wrow = (blk * 4 + wave) * 16;
    if (wrow >= N_NODES) return;
    int l15 = lane & 15, lg = lane >> 4;

    f32x4 acc[7];
    #pragma unroll
    for (int nt = 0; nt < 7; ++nt) acc[nt] = (f32x4){0.f, 0.f, 0.f, 0.f};

    #pragma unroll
    for (int ks = 0; ks < KSTEPS; ++ks) {
        s16x8 a;
        if (AF32) {
            const float* arow = (const float*)Aptr + (size_t)(wrow + l15) * strideA + lg * 8 + ks * 32;
            float4 f0 = *(const float4*)arow;
            float4 f1 = *(const float4*)(arow + 4);
            a[0] = (short)bf16_rne(f0.x); a[1] = (short)bf16_rne(f0.y);
            a[2] = (short)bf16_rne(f0.z); a[3] = (short)bf16_rne(f0.w);
            a[4] = (short)bf16_rne(f1.x); a[5] = (short)bf16_rne(f1.y);
            a[6] = (short)bf16_rne(f1.z); a[7] = (short)bf16_rne(f1.w);
        } else {
            const unsigned short* arow = (const unsigned short*)Aptr + (size_t)(wrow + l15) * strideA + lg * 8;
            a = *(const s16x8*)(arow + ks * 32);
        }
        const unsigned short* wp = Wf + ((size_t)(ks * 7) * 64 + lane) * 8;
        #pragma unroll
        for (int nt = 0; nt < 7; ++nt) {
            s16x8 bfr = *(const s16x8*)(wp + (size_t)nt * 512);
            acc[nt] = __builtin_amdgcn_mfma_f32_16x16x32_bf16(a, bfr, acc[nt], 0, 0, 0);
        }
    }

    // D layout: col = nt*16 + l15, row(local) = lg*4 + r
    float vals[7][4];
    if (EPI == 0) {                                   // embed: + bias
        #pragma unroll
        for (int nt = 0; nt < 7; ++nt) {
            int col = nt * 16 + l15;
            float bv = (col < HD) ? bias[col] : 0.0f;
            #pragma unroll
            for (int r = 0; r < 4; ++r) vals[nt][r] = acc[nt][r] + bv;
        }
    } else {                                          // apply: norm + residual
        float ss[4] = {0.f, 0.f, 0.f, 0.f};
        #pragma unroll
        for (int nt = 0; nt < 7; ++nt) {
            int col = nt * 16 + l15;
            bool valid = (col < HD);
            float bv = valid ? bias[col] : 0.0f;
            #pragma unroll
            for (int r = 0; r < 4; ++r) {
                float v = valid ? (acc[nt][r] + bv) : 0.0f;
                vals[nt][r] = v;
                ss[r] += v * v;
            }
        }
        #pragma unroll
        for (int r = 0; r < 4; ++r) {
            ss[r] += __shfl_xor(ss[r], 1);
            ss[r] += __shfl_xor(ss[r], 2);
            ss[r] += __shfl_xor(ss[r], 4);
            ss[r] += __shfl_xor(ss[r], 8);
        }
        float rn[4];
        #pragma unroll
        for (int r = 0; r < 4; ++r) rn[r] = 1.0f / fmaxf(sqrtf(ss[r]), 1e-12f);
        #pragma unroll
        for (int nt = 0; nt < 7; ++nt) {
            int col = nt * 16 + l15;
            bool valid = (col < HD);
            #pragma unroll
            for (int r = 0; r < 4; ++r) {
                int row = wrow + lg * 4 + r;
                float hv = valid ? bf16_to_f(hc[(size_t)row * 224 + col]) : 0.0f;
                vals[nt][r] = hv + fmaxf(vals[nt][r] * rn[r], 0.0f);
            }
        }
    }

    if (EPI == 3) {                                   // graph-mean accumulation
        int g0 = gids[wrow], g15 = gids[wrow + 15];
        if (g0 == g15) {
            #pragma unroll
            for (int nt = 0; nt < 7; ++nt) {
                int col = nt * 16 + l15;
                float cs = vals[nt][0] + vals[nt][1] + vals[nt][2] + vals[nt][3];
                cs += __shfl_xor(cs, 16);
                cs += __shfl_xor(cs, 32);
                if (lane < 16 && col < HD) atomicAdd(&gsum[g0 * HD + col], cs);
            }
        } else {
            int gr[4];
            #pragma unroll
            for (int r = 0; r < 4; ++r) gr[r] = gids[wrow + lg * 4 + r];
            #pragma unroll
            for (int nt = 0; nt < 7; ++nt) {
                int col = nt * 16 + l15;
                if (col >= HD) continue;
                #pragma unroll
                for (int r = 0; r < 4; ++r)
                    atomicAdd(&gsum[gr[r] * HD + col], vals[nt][r]);
            }
        }
        return;
    }

    // transpose h into LDS (cols >=108 forced 0), zero pad cols 112..127
    #pragma unroll
    for (int nt = 0; nt < 7; ++nt) {
        int col = nt * 16 + l15;
        #pragma unroll
        for (int r = 0; r < 4; ++r) {
            unsigned short hb = (col < HD) ? bf16_rne(vals[nt][r]) : 0;
            s_t[wave][lg * 4 + r][col] = hb;
        }
    }
    #pragma unroll
    for (int p = 0; p < 2; ++p) {                     // 16 rows x 8 uints (cols 112..127)
        int idx = p * 64 + lane;
        int row = idx >> 3, q = idx & 7;
        *(unsigned*)&s_t[wave][row][112 + q * 2] = 0u;
    }

    // h store: 14 segs x 16B per row
    #pragma unroll
    for (int p = 0; p < 4; ++p) {
        int seg = p * 4 + lg;
        if (seg < 14)
            *(s16x8*)(hc + (size_t)(wrow + l15) * 224 + seg * 8) =
                *(const s16x8*)&s_t[wave][l15][seg * 8];
    }

    // pool: m = relu(h @ Wp + bp), A-fragments from LDS transpose
    f32x4 accp[7];
    #pragma unroll
    for (int nt = 0; nt < 7; ++nt) accp[nt] = (f32x4){0.f, 0.f, 0.f, 0.f};
    #pragma unroll
    for (int ks = 0; ks < 4; ++ks) {
        s16x8 a = *(const s16x8*)&s_t[wave][l15][ks * 32 + lg * 8];
        const unsigned short* wp = Wfp + ((size_t)(ks * 7) * 64 + lane) * 8;
        #pragma unroll
        for (int nt = 0; nt < 7; ++nt) {
            s16x8 bfr = *(const s16x8*)(wp + (size_t)nt * 512);
            accp[nt] = __builtin_amdgcn_mfma_f32_16x16x32_bf16(a, bfr, accp[nt], 0, 0, 0);
        }
    }
    // transpose m into LDS, then chunked aligned 16B stores
    #pragma unroll
    for (int nt = 0; nt < 7; ++nt) {
        int col = nt * 16 + l15;
        float bv = (col < HD) ? biasp[col] : 0.0f;
        #pragma unroll
        for (int r = 0; r < 4; ++r)
            s_t[wave][lg * 4 + r][col] = bf16_rne(fmaxf(accp[nt][r] + bv, 0.0f));
    }
    #pragma unroll
    for (int p = 0; p < 4; ++p) {
        int seg = p * 4 + lg;
        if (seg < 14) {
            int ch = seg >> 2, sub = seg & 3;
            *(s16x8*)(m_out + ((size_t)ch * N_NODES + (wrow + l15)) * 32 + sub * 8) =
                *(const s16x8*)&s_t[wave][l15][seg * 8];
        }
    }
}

template <int KSTEPS, int EPI>
__global__ __launch_bounds__(256) void gemm_k(
    const unsigned short* __restrict__ A, int strideA,
    const unsigned short* __restrict__ Wf, const float* __restrict__ bias,
    const unsigned short* __restrict__ Wfp, const float* __restrict__ biasp,
    unsigned short* __restrict__ hc, unsigned short* __restrict__ m_out,
    const int* __restrict__ gids, float* __restrict__ gsum) {
    gemm_body<KSTEPS, EPI, false>(blockIdx.x, A, strideA, Wf, bias, Wfp, biasp,
                                  hc, m_out, gids, gsum);
}

// ---------------------------------------------------------------------------
// mix: edge counting (returning atomics on 16B-padded counters, overlapped
// with the GEMM) || embed(f32 A)+pool1 (MFMA) — independent work, one dispatch
// ---------------------------------------------------------------------------
__global__ __launch_bounds__(256) void mix_k(
    const int* __restrict__ dst, int* __restrict__ deg_p, int* __restrict__ pos,
    const float* __restrict__ feat,
    const unsigned short* __restrict__ Wf_emb, const float* __restrict__ bemb,
    const unsigned short* __restrict__ Wf_p1, const float* __restrict__ bp1,
    unsigned short* __restrict__ hc, unsigned short* __restrict__ m_out) {
    if (blockIdx.x < CNT_B) {
        int e = blockIdx.x * 256 + threadIdx.x;
        if (e < N_EDGES) pos[e] = atomicAdd(&deg_p[(size_t)dst[e] * DEGP], 1);
    } else {
        gemm_body<2, 0, true>(blockIdx.x - CNT_B, feat, FIN, Wf_emb, bemb,
                              Wf_p1, bp1, hc, m_out, nullptr, nullptr);
    }
}

// ---------------------------------------------------------------------------
// Chunked, software-pipelined aggregation (round-9 structure), boff inline.
// ---------------------------------------------------------------------------
__global__ __launch_bounds__(256) void aggregate_k(
    const unsigned short* __restrict__ m,
    const int* __restrict__ rowp, const int* __restrict__ boff,
    const int* __restrict__ csr, unsigned short* __restrict__ hc) {
    int chunk = blockIdx.x & 3;
    int nblk  = blockIdx.x >> 2;
    int t = threadIdx.x, lane = t & 63, wave = t >> 6;
    int v = nblk * 64 + wave * 16 + (lane >> 2);
    if (v >= N_NODES) return;
    int sub = lane & 3;
    int co = sub * 8;                                 // within-chunk col offset
    int gcol = chunk * 32 + co;                       // global m/c column
    bool active = (gcol < 112);                       // chunk-3 upper half: mask only
    int grp = lane & ~3;
    const unsigned short* mc = m + (size_t)chunk * N_NODES * 32 + co;
    int beg = rowp[v] + boff[v >> 10];
    int end = (v + 1 < N_NODES) ? rowp[v + 1] + boff[(v + 1) >> 10] : rowp[N_NODES];
    float s[8] = {0.f, 0.f, 0.f, 0.f, 0.f, 0.f, 0.f, 0.f};

    int i = beg;
    int p0 = i + sub, p1 = i + 4 + sub;
    int c0 = (p0 < end) ? csr[p0] : -1;
    int c1 = (p1 < end) ? csr[p1] : -1;
    while (i < end) {
        int ni = i + 8;
        int n0 = -1, n1 = -1;
        if (ni < end) {                               // prefetch next batch early
            int q0 = ni + sub, q1 = ni + 4 + sub;
            n0 = (q0 < end) ? csr[q0] : -1;
            n1 = (q1 < end) ? csr[q1] : -1;
        }
        #pragma unroll
        for (int j = 0; j < 4; ++j) {
            int sv = __shfl(c0, grp + j);
            if (sv >= 0 && active) {
                s16x8 a = *(const s16x8*)(mc + (size_t)sv * 32);
                #pragma unroll
                for (int q = 0; q < 8; ++q) s[q] += bf16_to_f((unsigned short)a[q]);
            }
        }
        #pragma unroll
        for (int j = 0; j < 4; ++j) {
            int sv = __shfl(c1, grp + j);
            if (sv >= 0 && active) {
                s16x8 a = *(const s16x8*)(mc + (size_t)sv * 32);
                #pragma unroll
                for (int q = 0; q < 8; ++q) s[q] += bf16_to_f((unsigned short)a[q]);
            }
        }
        c0 = n0; c1 = n1; i = ni;
    }

    if (active) {
        int degv = end - beg;
        float inv = (degv > 0) ? 1.0f / (float)degv : 0.0f;
        unsigned short* dstp = hc + (size_t)v * 224 + HD + gcol;
        #pragma unroll
        for (int j2 = 0; j2 < 4; ++j2) {
            unsigned pk = (unsigned)bf16_rne(s[2 * j2] * inv) |
                          ((unsigned)bf16_rne(s[2 * j2 + 1] * inv) << 16);
            *(unsigned*)(dstp + 2 * j2) = pk;
        }
    }
}

__global__ void finalize_k(const float* __restrict__ gsum, const int* __restrict__ gcnt,
                           float* __restrict__ out) {
    int i = blockIdx.x * 256 + threadIdx.x;
    if (i < NG * HD) {
        int g = i / HD;
        int cnt = gcnt[g];
        float inv = (cnt > 0) ? 1.0f / (float)cnt : 0.0f;
        out[i] = gsum[i] * inv;
    }
}

// ---------------------------------------------------------------------------
extern "C" void kernel_launch(void* const* d_in, const int* in_sizes, int n_in,
                              void* d_out, int out_size, void* d_ws, size_t ws_size,
                              hipStream_t stream) {
    const float* feat = (const float*)d_in[0];
    const int* src  = (const int*)d_in[4];
    const int* dst  = (const int*)d_in[5];
    const int* gids = (const int*)d_in[6];
    const float* Wemb = (const float*)d_in[7];
    const float* bemb = (const float*)d_in[8];
    const float* Wp1  = (const float*)d_in[9];
    const float* bp1  = (const float*)d_in[10];
    const float* Wn1  = (const float*)d_in[11];
    const float* bn1  = (const float*)d_in[12];
    const float* Wp2  = (const float*)d_in[13];
    const float* bp2  = (const float*)d_in[14];
    const float* Wn2  = (const float*)d_in[15];
    const float* bn2  = (const float*)d_in[16];
    float* out = (float*)d_out;
    (void)in_sizes; (void)n_in; (void)out_size; (void)ws_size;

    char* ws = (char*)d_ws;
    size_t off = 0;
    auto carve = [&](size_t bytes) -> char* {
        char* p = ws + off;
        off = (off + bytes + 255) & ~(size_t)255;
        return p;
    };
    unsigned short* hc    = (unsigned short*)carve((size_t)N_NODES * 224 * 2);
    unsigned short* m_bf  = (unsigned short*)carve((size_t)4 * N_NODES * 32 * 2);
    unsigned short* Wf    = (unsigned short*)carve((size_t)24 * 7 * 512 * 2);
    int* deg_p = (int*)carve((size_t)N_NODES * DEGP * 4);
    int* rowp  = (int*)carve((size_t)(N_NODES + 1) * 4);
    int* pos   = (int*)carve((size_t)N_EDGES * 4);
    int* csr   = (int*)carve((size_t)N_EDGES * 4);
    int* bsum  = (int*)carve((size_t)SCAN_B * 4);
    int* boff  = (int*)carve((size_t)SCAN_B * 4);
    float* gsum = (float*)carve((size_t)NG * HD * 4);
    int*   gcnt = (int*)carve((size_t)NG * 4);
    int*   done = (int*)carve(4);

    // fused prep: hc-pad + repack + deg_p/gsum/done zero + gcnt (no fconv!)
    prep_k<<<449, 256, 0, stream>>>(hc, Wemb, Wp1, Wn1, Wp2, Wn2, Wf,
                                    deg_p, gsum, gids, gcnt, done);

    const int GB = (N_NODES / 16 + 3) / 4;           // 782 blocks x 4 waves
    const int AB = 4 * ((N_NODES + 63) / 64);        // 4 chunks x 782 node-blocks
    unsigned short* Wf_emb = Wf + (size_t)0  * 7 * 512;
    unsigned short* Wf_p1  = Wf + (size_t)2  * 7 * 512;
    unsigned short* Wf_n1  = Wf + (size_t)6  * 7 * 512;
    unsigned short* Wf_p2  = Wf + (size_t)13 * 7 * 512;
    unsigned short* Wf_n2  = Wf + (size_t)17 * 7 * 512;

    // count (returning atomics, padded) || embed(f32)+pool1 in one dispatch
    mix_k<<<CNT_B + GB, 256, 0, stream>>>(dst, deg_p, pos, feat, Wf_emb, bemb,
                                          Wf_p1, bp1, hc, m_bf);

    scan1_k<<<SCAN_B, 1024, 0, stream>>>(deg_p, rowp, bsum, boff, done);
    fill_k<<<CNT_B, 256, 0, stream>>>(src, dst, rowp, boff, pos, csr);

    // layer 1
    aggregate_k<<<AB, 256, 0, stream>>>(m_bf, rowp, boff, csr, hc);
    gemm_k<7, 2><<<GB, 256, 0, stream>>>(hc, 224, Wf_n1, bn1, Wf_p2, bp2,
                                         hc, m_bf, nullptr, nullptr);
    // layer 2
    aggregate_k<<<AB, 256, 0, stream>>>(m_bf, rowp, boff, csr, hc);
    gemm_k<7, 3><<<GB, 256, 0, stream>>>(hc, 224, Wf_n2, bn2, nullptr, nullptr,
                                         hc, nullptr, gids, gsum);

    finalize_k<<<(NG * HD + 255) / 256, 256, 0, stream>>>(gsum, gcnt, out);
}